// Round 1
// baseline (625.666 us; speedup 1.0000x reference)
//
#include <hip/hip_runtime.h>
#include <cmath>

#define Hdim 512
#define Udim 32
#define Bdim 32
#define Tdim 2048
#define RM   128   // rows per block in K1
#define KC   32    // k-chunk
#define LDX  36    // padded LDS row stride (floats) for x/t tiles -> conflict-free b128 reads

// ---------------- Kernel 1: gamma/beta GEMMs + tanh + lambd combine -> delta [B*T, U] ----------
__global__ __launch_bounds__(256, 2) void k1_gemm_act(
    const float* __restrict__ x, const float* __restrict__ tin,
    const float* __restrict__ kx, const float* __restrict__ kt,
    const float* __restrict__ bx, const float* __restrict__ bt,
    const float* __restrict__ lambd, float* __restrict__ delta)
{
    __shared__ float xs[RM * LDX];
    __shared__ float ts[RM * LDX];
    __shared__ float kxs[KC * Udim];
    __shared__ float kts[KC * Udim];

    const int tid   = threadIdx.x;
    const int u_thr = tid & 7;        // 8 u-thread groups -> u0 = 4*u_thr
    const int r_thr = tid >> 3;       // 0..31 ; rows r_thr + 32*j
    const int u0    = u_thr * 4;
    const int row0  = blockIdx.x * RM;

    // staging load mapping: lrow = tid>>3 (0..31), lk4 = tid&7 (float4 within 32-float k-chunk row)
    const int lk4  = tid & 7;
    const int lrow = tid >> 3;

    const float4* xg  = (const float4*)x;
    const float4* tg  = (const float4*)tin;
    const float4* kxg = (const float4*)kx;
    const float4* ktg = (const float4*)kt;

    float4 px[4], pt[4], pwx, pwt;

    float accx[4][4];
    float acct[4][4];
#pragma unroll
    for (int j = 0; j < 4; ++j)
#pragma unroll
        for (int uu = 0; uu < 4; ++uu) { accx[j][uu] = 0.f; acct[j][uu] = 0.f; }

    // prefetch chunk 0
#pragma unroll
    for (int l = 0; l < 4; ++l) {
        const size_t row = (size_t)(row0 + lrow + 32 * l);
        px[l] = xg[row * (Hdim / 4) + lk4];
        pt[l] = tg[row * (Hdim / 4) + lk4];
    }
    pwx = kxg[(size_t)lrow * (Udim / 4) + lk4];
    pwt = ktg[(size_t)lrow * (Udim / 4) + lk4];

#pragma unroll 1
    for (int c = 0; c < Hdim / KC; ++c) {
        __syncthreads();
#pragma unroll
        for (int l = 0; l < 4; ++l) {
            *(float4*)&xs[(lrow + 32 * l) * LDX + lk4 * 4] = px[l];
            *(float4*)&ts[(lrow + 32 * l) * LDX + lk4 * 4] = pt[l];
        }
        *(float4*)&kxs[lrow * Udim + lk4 * 4] = pwx;
        *(float4*)&kts[lrow * Udim + lk4 * 4] = pwt;
        __syncthreads();

        if (c + 1 < Hdim / KC) {
            const int cn = c + 1;
#pragma unroll
            for (int l = 0; l < 4; ++l) {
                const size_t row = (size_t)(row0 + lrow + 32 * l);
                px[l] = xg[row * (Hdim / 4) + cn * (KC / 4) + lk4];
                pt[l] = tg[row * (Hdim / 4) + cn * (KC / 4) + lk4];
            }
            pwx = kxg[(size_t)(cn * KC + lrow) * (Udim / 4) + lk4];
            pwt = ktg[(size_t)(cn * KC + lrow) * (Udim / 4) + lk4];
        }

#pragma unroll
        for (int q = 0; q < KC / 4; ++q) {
            const int k0 = q * 4;
            float wx[4][4], wt[4][4], ax[4][4], at_[4][4];
#pragma unroll
            for (int kk = 0; kk < 4; ++kk) {
                float4 vx = *(const float4*)&kxs[(k0 + kk) * Udim + u0];
                wx[kk][0] = vx.x; wx[kk][1] = vx.y; wx[kk][2] = vx.z; wx[kk][3] = vx.w;
                float4 vt = *(const float4*)&kts[(k0 + kk) * Udim + u0];
                wt[kk][0] = vt.x; wt[kk][1] = vt.y; wt[kk][2] = vt.z; wt[kk][3] = vt.w;
            }
#pragma unroll
            for (int j = 0; j < 4; ++j) {
                float4 va = *(const float4*)&xs[(r_thr + 32 * j) * LDX + k0];
                ax[j][0] = va.x; ax[j][1] = va.y; ax[j][2] = va.z; ax[j][3] = va.w;
                float4 vb = *(const float4*)&ts[(r_thr + 32 * j) * LDX + k0];
                at_[j][0] = vb.x; at_[j][1] = vb.y; at_[j][2] = vb.z; at_[j][3] = vb.w;
            }
#pragma unroll
            for (int j = 0; j < 4; ++j)
#pragma unroll
                for (int kk = 0; kk < 4; ++kk)
#pragma unroll
                    for (int uu = 0; uu < 4; ++uu) {
                        accx[j][uu] = fmaf(ax[j][kk], wx[kk][uu], accx[j][uu]);
                        acct[j][uu] = fmaf(at_[j][kk], wt[kk][uu], acct[j][uu]);
                    }
        }
    }

    // epilogue: tanh + lambd combine, write delta
    float4 bxv = *(const float4*)&bx[u0];
    float4 btv = *(const float4*)&bt[u0];
    float bxa[4] = { bxv.x, bxv.y, bxv.z, bxv.w };
    float bta[4] = { btv.x, btv.y, btv.z, btv.w };

#pragma unroll
    for (int j = 0; j < 4; ++j) {
        const int grow = row0 + r_thr + 32 * j;
        const float lam = lambd[grow & (Tdim - 1)];
        float o[4];
#pragma unroll
        for (int uu = 0; uu < 4; ++uu) {
            float g  = tanhf(accx[j][uu] + bxa[uu]);
            float be = tanhf(acct[j][uu] + bta[uu]);
            o[uu] = lam * g + (1.0f - lam) * be;
        }
        *(float4*)&delta[(size_t)grow * Udim + u0] = make_float4(o[0], o[1], o[2], o[3]);
    }
}

// ---------------- Kernel 2: scores = delta @ kernel_a, softmax over T, write alpha -------------
// grid: 256 blocks, blockIdx.x = ht*32 + b  (so XCD = b % 8 -> all h-tiles of b share an XCD's L2)
// block: 512 threads = 8 waves; tx = h within 64-wide tile, ty = wave -> contiguous T-chunk of 256
__global__ __launch_bounds__(512) void k2_softmax(
    const float* __restrict__ delta, const float* __restrict__ ka_g,
    float* __restrict__ alpha)
{
    const int tid = threadIdx.x;
    const int tx  = tid & 63;
    const int ty  = tid >> 6;          // 0..7
    const int bidx = blockIdx.x;
    const int b  = bidx & 31;
    const int ht = bidx >> 5;          // 0..7
    const int h  = ht * 64 + tx;

    // kernel_a column for this lane's h, kept in 32 VGPRs
    float ka[Udim];
#pragma unroll
    for (int u = 0; u < Udim; ++u) ka[u] = ka_g[u * Hdim + h];

    const int tbeg = ty * (Tdim / 8);
    const float* dbase = delta + (size_t)b * Tdim * Udim;

    float m = -1e30f, l = 0.f;
    for (int i = 0; i < Tdim / 8; ++i) {
        const int t = tbeg + i;
        const float4* dp = (const float4*)(dbase + (size_t)t * Udim);
        float4 q[8];
#pragma unroll
        for (int j = 0; j < 8; ++j) q[j] = dp[j];
        float d[Udim];
#pragma unroll
        for (int j = 0; j < 8; ++j) {
            d[4 * j] = q[j].x; d[4 * j + 1] = q[j].y; d[4 * j + 2] = q[j].z; d[4 * j + 3] = q[j].w;
        }
        float s0 = 0.f, s1 = 0.f, s2 = 0.f, s3 = 0.f;
#pragma unroll
        for (int u = 0; u < Udim; u += 4) {
            s0 = fmaf(d[u],     ka[u],     s0);
            s1 = fmaf(d[u + 1], ka[u + 1], s1);
            s2 = fmaf(d[u + 2], ka[u + 2], s2);
            s3 = fmaf(d[u + 3], ka[u + 3], s3);
        }
        const float s = (s0 + s1) + (s2 + s3);
        const float mn = fmaxf(m, s);
        l = l * __expf(m - mn) + __expf(s - mn);
        m = mn;
    }

    // merge (m,l) across the 8 waves (per h column)
    __shared__ float ms[8][64];
    __shared__ float ls[8][64];
    ms[ty][tx] = m;
    ls[ty][tx] = l;
    __syncthreads();
    float M = -1e30f;
#pragma unroll
    for (int w = 0; w < 8; ++w) M = fmaxf(M, ms[w][tx]);
    float L = 0.f;
#pragma unroll
    for (int w = 0; w < 8; ++w) L += ls[w][tx] * __expf(ms[w][tx] - M);
    const float rinv = 1.0f / L;

    float* abase = alpha + (size_t)b * Tdim * Hdim + h;
    for (int i = 0; i < Tdim / 8; ++i) {
        const int t = tbeg + i;
        const float4* dp = (const float4*)(dbase + (size_t)t * Udim);
        float4 q[8];
#pragma unroll
        for (int j = 0; j < 8; ++j) q[j] = dp[j];
        float d[Udim];
#pragma unroll
        for (int j = 0; j < 8; ++j) {
            d[4 * j] = q[j].x; d[4 * j + 1] = q[j].y; d[4 * j + 2] = q[j].z; d[4 * j + 3] = q[j].w;
        }
        float s0 = 0.f, s1 = 0.f, s2 = 0.f, s3 = 0.f;
#pragma unroll
        for (int u = 0; u < Udim; u += 4) {
            s0 = fmaf(d[u],     ka[u],     s0);
            s1 = fmaf(d[u + 1], ka[u + 1], s1);
            s2 = fmaf(d[u + 2], ka[u + 2], s2);
            s3 = fmaf(d[u + 3], ka[u + 3], s3);
        }
        const float s = (s0 + s1) + (s2 + s3);
        abase[(size_t)t * Hdim] = __expf(s - M) * rinv;
    }
}

extern "C" void kernel_launch(void* const* d_in, const int* in_sizes, int n_in,
                              void* d_out, int out_size, void* d_ws, size_t ws_size,
                              hipStream_t stream) {
    const float* x     = (const float*)d_in[0];
    const float* tin   = (const float*)d_in[1];
    const float* kx    = (const float*)d_in[2];
    const float* kt    = (const float*)d_in[3];
    const float* ka    = (const float*)d_in[4];
    const float* bx    = (const float*)d_in[5];
    const float* bt    = (const float*)d_in[6];
    const float* lambd = (const float*)d_in[7];
    float* alpha = (float*)d_out;
    float* delta = (float*)d_ws;   // needs B*T*U*4 = 8 MB

    k1_gemm_act<<<(Bdim * Tdim) / RM, 256, 0, stream>>>(x, tin, kx, kt, bx, bt, lambd, delta);
    k2_softmax<<<256, 512, 0, stream>>>(delta, ka, alpha);
}

// Round 2
// 468.352 us; speedup vs baseline: 1.3359x; 1.3359x over previous
//
#include <hip/hip_runtime.h>
#include <cmath>

#define Hdim 512
#define Udim 32
#define Bdim 32
#define Tdim 2048
#define RM   64    // rows per block in K1
#define KC   32    // k-chunk
#define LDX  36    // padded LDS row stride (floats)
#define CH   128   // delta rows per LDS chunk in K2

// ---------------- Kernel 1: gamma/beta GEMMs + tanh + lambd combine -> delta [B*T, U] ----------
__global__ __launch_bounds__(256, 3) void k1_gemm_act(
    const float* __restrict__ x, const float* __restrict__ tin,
    const float* __restrict__ kx, const float* __restrict__ kt,
    const float* __restrict__ bx, const float* __restrict__ bt,
    const float* __restrict__ lambd, float* __restrict__ delta)
{
    __shared__ float xs[RM * LDX];
    __shared__ float ts[RM * LDX];
    __shared__ float kxs[KC * Udim];
    __shared__ float kts[KC * Udim];

    const int tid   = threadIdx.x;
    const int u0    = (tid & 7) * 4;
    const int r_thr = tid >> 3;       // 0..31 ; rows r_thr + 32*j, j in {0,1}
    const int row0  = blockIdx.x * RM;
    const int lk4   = tid & 7;
    const int lrow  = tid >> 3;

    const float4* xg  = (const float4*)x;
    const float4* tg  = (const float4*)tin;
    const float4* kxg = (const float4*)kx;
    const float4* ktg = (const float4*)kt;

    float4 px[2], pt[2], pwx, pwt;
    float accx[2][4], acct[2][4];
#pragma unroll
    for (int j = 0; j < 2; ++j)
#pragma unroll
        for (int uu = 0; uu < 4; ++uu) { accx[j][uu] = 0.f; acct[j][uu] = 0.f; }

    // prefetch chunk 0
#pragma unroll
    for (int l = 0; l < 2; ++l) {
        const size_t row = (size_t)(row0 + lrow + 32 * l);
        px[l] = xg[row * (Hdim / 4) + lk4];
        pt[l] = tg[row * (Hdim / 4) + lk4];
    }
    pwx = kxg[(size_t)lrow * (Udim / 4) + lk4];
    pwt = ktg[(size_t)lrow * (Udim / 4) + lk4];

#pragma unroll 1
    for (int c = 0; c < Hdim / KC; ++c) {
        __syncthreads();
#pragma unroll
        for (int l = 0; l < 2; ++l) {
            *(float4*)&xs[(lrow + 32 * l) * LDX + lk4 * 4] = px[l];
            *(float4*)&ts[(lrow + 32 * l) * LDX + lk4 * 4] = pt[l];
        }
        *(float4*)&kxs[lrow * Udim + lk4 * 4] = pwx;
        *(float4*)&kts[lrow * Udim + lk4 * 4] = pwt;
        __syncthreads();

        if (c + 1 < Hdim / KC) {
            const int cn = c + 1;
#pragma unroll
            for (int l = 0; l < 2; ++l) {
                const size_t row = (size_t)(row0 + lrow + 32 * l);
                px[l] = xg[row * (Hdim / 4) + cn * (KC / 4) + lk4];
                pt[l] = tg[row * (Hdim / 4) + cn * (KC / 4) + lk4];
            }
            pwx = kxg[(size_t)(cn * KC + lrow) * (Udim / 4) + lk4];
            pwt = ktg[(size_t)(cn * KC + lrow) * (Udim / 4) + lk4];
        }

#pragma unroll
        for (int q = 0; q < KC / 4; ++q) {
            const int k0 = q * 4;
            float wx[4][4], wt[4][4], ax[2][4], at_[2][4];
#pragma unroll
            for (int kk = 0; kk < 4; ++kk) {
                float4 vx = *(const float4*)&kxs[(k0 + kk) * Udim + u0];
                wx[kk][0] = vx.x; wx[kk][1] = vx.y; wx[kk][2] = vx.z; wx[kk][3] = vx.w;
                float4 vt = *(const float4*)&kts[(k0 + kk) * Udim + u0];
                wt[kk][0] = vt.x; wt[kk][1] = vt.y; wt[kk][2] = vt.z; wt[kk][3] = vt.w;
            }
#pragma unroll
            for (int j = 0; j < 2; ++j) {
                float4 va = *(const float4*)&xs[(r_thr + 32 * j) * LDX + k0];
                ax[j][0] = va.x; ax[j][1] = va.y; ax[j][2] = va.z; ax[j][3] = va.w;
                float4 vb = *(const float4*)&ts[(r_thr + 32 * j) * LDX + k0];
                at_[j][0] = vb.x; at_[j][1] = vb.y; at_[j][2] = vb.z; at_[j][3] = vb.w;
            }
#pragma unroll
            for (int j = 0; j < 2; ++j)
#pragma unroll
                for (int kk = 0; kk < 4; ++kk)
#pragma unroll
                    for (int uu = 0; uu < 4; ++uu) {
                        accx[j][uu] = fmaf(ax[j][kk], wx[kk][uu], accx[j][uu]);
                        acct[j][uu] = fmaf(at_[j][kk], wt[kk][uu], acct[j][uu]);
                    }
        }
    }

    // epilogue
    float4 bxv = *(const float4*)&bx[u0];
    float4 btv = *(const float4*)&bt[u0];
    float bxa[4] = { bxv.x, bxv.y, bxv.z, bxv.w };
    float bta[4] = { btv.x, btv.y, btv.z, btv.w };

#pragma unroll
    for (int j = 0; j < 2; ++j) {
        const int grow = row0 + r_thr + 32 * j;
        const float lam = lambd[grow & (Tdim - 1)];
        float o[4];
#pragma unroll
        for (int uu = 0; uu < 4; ++uu) {
            float g  = tanhf(accx[j][uu] + bxa[uu]);
            float be = tanhf(acct[j][uu] + bta[uu]);
            o[uu] = lam * g + (1.0f - lam) * be;
        }
        *(float4*)&delta[(size_t)grow * Udim + u0] = make_float4(o[0], o[1], o[2], o[3]);
    }
}

// ---------------- Kernel 2: scores = delta @ kernel_a, softmax over T -> alpha -----------------
// grid: 256 blocks, blockIdx.x = ht*32 + b (XCD = b%8 -> same-b blocks share an XCD L2)
// block: 1024 threads = 16 waves; tx = h lane (64 h per block), ty = wave
// delta staged through LDS in 128-row double-buffered chunks; each wave handles rows t%16==ty.
__global__ __launch_bounds__(1024, 2) void k2_softmax(
    const float* __restrict__ delta, const float* __restrict__ ka_g,
    float* __restrict__ alpha)
{
    __shared__ float dsm[2][CH * Udim];   // 2 x 16 KB
    __shared__ float ms[16][64];
    __shared__ float ls[16][64];

    const int tid = threadIdx.x;
    const int tx  = tid & 63;
    const int ty  = tid >> 6;          // 0..15
    const int b   = blockIdx.x & 31;
    const int ht  = blockIdx.x >> 5;   // 0..7
    const int h   = ht * 64 + tx;

    // kernel_a column for this lane's h (32 VGPRs)
    float ka[Udim];
#pragma unroll
    for (int u = 0; u < Udim; ++u) ka[u] = ka_g[u * Hdim + h];

    const float4* dsrc = (const float4*)(delta + (size_t)b * Tdim * Udim);

    // ---- pass 1: online (m, l) ----
    ((float4*)dsm[0])[tid] = dsrc[tid];   // stage chunk 0 (1024 float4 = 128 rows)

    float m = -1e30f, l = 0.f;
#pragma unroll 1
    for (int c = 0; c < Tdim / CH; ++c) {
        __syncthreads();
        const float* cur = dsm[c & 1];
        if (c + 1 < Tdim / CH)
            ((float4*)dsm[(c + 1) & 1])[tid] = dsrc[(size_t)(c + 1) * (CH * Udim / 4) + tid];
#pragma unroll
        for (int i = 0; i < CH / 16; ++i) {
            const int r = ty + 16 * i;
            const float4* dp = (const float4*)(cur + r * Udim);
            float4 q[8];
#pragma unroll
            for (int j = 0; j < 8; ++j) q[j] = dp[j];
            float s0 = 0.f, s1 = 0.f, s2 = 0.f, s3 = 0.f;
#pragma unroll
            for (int j = 0; j < 8; ++j) {
                s0 = fmaf(q[j].x, ka[4 * j],     s0);
                s1 = fmaf(q[j].y, ka[4 * j + 1], s1);
                s2 = fmaf(q[j].z, ka[4 * j + 2], s2);
                s3 = fmaf(q[j].w, ka[4 * j + 3], s3);
            }
            const float s = (s0 + s1) + (s2 + s3);
            const float mn = fmaxf(m, s);
            l = l * __expf(m - mn) + __expf(s - mn);
            m = mn;
        }
    }

    ms[ty][tx] = m;
    ls[ty][tx] = l;
    __syncthreads();
    float M = -1e30f;
#pragma unroll
    for (int w = 0; w < 16; ++w) M = fmaxf(M, ms[w][tx]);
    float L = 0.f;
#pragma unroll
    for (int w = 0; w < 16; ++w) L += ls[w][tx] * __expf(ms[w][tx] - M);
    const float rinv = 1.0f / L;

    // ---- pass 2: recompute scores, write alpha ----
    ((float4*)dsm[0])[tid] = dsrc[tid];   // restage chunk 0 (dsm[0] idle since c=14 sync)

    float* abase = alpha + (size_t)b * Tdim * Hdim + h;
#pragma unroll 1
    for (int c = 0; c < Tdim / CH; ++c) {
        __syncthreads();
        const float* cur = dsm[c & 1];
        if (c + 1 < Tdim / CH)
            ((float4*)dsm[(c + 1) & 1])[tid] = dsrc[(size_t)(c + 1) * (CH * Udim / 4) + tid];
#pragma unroll
        for (int i = 0; i < CH / 16; ++i) {
            const int r = ty + 16 * i;
            const int t = c * CH + r;
            const float4* dp = (const float4*)(cur + r * Udim);
            float4 q[8];
#pragma unroll
            for (int j = 0; j < 8; ++j) q[j] = dp[j];
            float s0 = 0.f, s1 = 0.f, s2 = 0.f, s3 = 0.f;
#pragma unroll
            for (int j = 0; j < 8; ++j) {
                s0 = fmaf(q[j].x, ka[4 * j],     s0);
                s1 = fmaf(q[j].y, ka[4 * j + 1], s1);
                s2 = fmaf(q[j].z, ka[4 * j + 2], s2);
                s3 = fmaf(q[j].w, ka[4 * j + 3], s3);
            }
            const float s = (s0 + s1) + (s2 + s3);
            abase[(size_t)t * Hdim] = __expf(s - M) * rinv;
        }
    }
}

extern "C" void kernel_launch(void* const* d_in, const int* in_sizes, int n_in,
                              void* d_out, int out_size, void* d_ws, size_t ws_size,
                              hipStream_t stream) {
    const float* x     = (const float*)d_in[0];
    const float* tin   = (const float*)d_in[1];
    const float* kx    = (const float*)d_in[2];
    const float* kt    = (const float*)d_in[3];
    const float* ka    = (const float*)d_in[4];
    const float* bx    = (const float*)d_in[5];
    const float* bt    = (const float*)d_in[6];
    const float* lambd = (const float*)d_in[7];
    float* alpha = (float*)d_out;
    float* delta = (float*)d_ws;   // B*T*U*4 = 8 MB

    k1_gemm_act<<<(Bdim * Tdim) / RM, 256, 0, stream>>>(x, tin, kx, kt, bx, bt, lambd, delta);
    k2_softmax<<<256, 1024, 0, stream>>>(delta, ka, alpha);
}